// Round 4
// baseline (248.810 us; speedup 1.0000x reference)
//
#include <hip/hip_runtime.h>

#define T_LEN   65536
#define BATCH   256
#define P       64
#define K1_LEN  8192
#define K1_THREADS 512
#define DBLK    256

typedef float f4 __attribute__((ext_vector_type(4)));

// ---------------------------------------------------------------------------
// means[t] = bias * R[t] where R is the STEP RESPONSE of the AR(64) filter:
//   R[t] = sum_k params[k]*R[t-1-k] + 1,  R[t<0] = 0
// Extension identity:
//   R[L+tau] = R[tau] + sum_{i=0}^{64} V[i]*R[tau-i]
//   V[i] = W[i]-W[i-1],  W[j] = sum_{m=0}^{63-j} params[m+j]*R[L-1-m]
// ---------------------------------------------------------------------------

// Phase 1a: serial 64 steps + in-LDS doubling 64 -> 8192, single workgroup.
// R3: the 65-tap FIR is split into two half-window passes (9 f4 regs live
// each) because the R2 single 17xf4 window made the allocator spill ~97
// floats/thread to scratch (337 KB traffic -> 116 us, VALU 95% idle).
// Spill traffic has tracked runtime 1:1 across R0/R2/R3 — keep live set small.
__global__ __launch_bounds__(K1_THREADS) void ar_k1(const float* __restrict__ params,
                                                    float* __restrict__ R) {
    __shared__ __align__(16) float Rl[K1_LEN];
    __shared__ float p[P];
    __shared__ __align__(16) float Vs[68];
    const int tid = threadIdx.x;
    if (tid < P) p[tid] = params[tid];
    __syncthreads();

    // Serial stage: lane k holds transposed-form state z_{k+1}.
    if (tid < 64) {
        float z = 0.f;
        const float pk = p[tid];
        for (int t = 0; t < 64; ++t) {
            float y  = __shfl(z, 0) + 1.0f;   // R[t]
            float zn = __shfl_down(z, 1);
            if (tid == 63) zn = 0.f;
            z = fmaf(pk, y, zn);
            if (tid == 0) Rl[t] = y;
        }
    }
    __syncthreads();

    for (int L = 64; L < K1_LEN; L <<= 1) {
        if (tid <= P) {
            const int j = tid;
            float W0 = 0.f, W1 = 0.f;
            if (j <= P - 1)
                for (int m = 0; m <= P - 1 - j; ++m) W0 = fmaf(p[m + j], Rl[L - 1 - m], W0);
            if (j >= 1)
                for (int m = 0; m <= P - j; ++m) W1 = fmaf(p[m + j - 1], Rl[L - 1 - m], W1);
            Vs[j] = W0 - W1;
        }
        __syncthreads();
        // boundary outputs tau in [0,64): R[tau-i]=0 for i>tau
        if (tid < 64) {
            const int tau = tid;
            float acc = Rl[tau];
            for (int i = 0; i <= tau; ++i) acc = fmaf(Vs[i], Rl[tau - i], acc);
            Rl[L + tau] = acc;
        }
        // blocked outputs tau in [64,L): 4 per quad. Window floats
        // Rl[4q..4q+67] = f4s w[0..16]; taps g use hi=w[16-g], lo=w[15-g].
        // Two passes: A uses w[8..16], B uses w[0..8] — 9 f4 live each.
        {
            const f4* __restrict__ Rl4 = reinterpret_cast<const f4*>(Rl);
            f4* __restrict__ Rl4w = reinterpret_cast<f4*>(Rl);
            const f4* __restrict__ V4 = reinterpret_cast<const f4*>(Vs);
            const int nq = (L - 64) >> 2;
            #pragma unroll 1
            for (int q = tid; q < nq; q += K1_THREADS) {
                float a0, a1, a2, a3;
                // ---- Phase A: g = 0..7, window f4s 8..16 ----
                {
                    f4 wA[9];
                    #pragma unroll
                    for (int j = 0; j < 9; ++j) wA[j] = Rl4[q + 8 + j];
                    a0 = wA[8].x; a1 = wA[8].y; a2 = wA[8].z; a3 = wA[8].w;
                    #pragma unroll
                    for (int g = 0; g < 8; ++g) {
                        const f4 v  = V4[g];
                        const f4 hi = wA[8 - g];
                        const f4 lo = wA[7 - g];
                        a0 = fmaf(v.x, hi.x, a0); a1 = fmaf(v.x, hi.y, a1);
                        a2 = fmaf(v.x, hi.z, a2); a3 = fmaf(v.x, hi.w, a3);
                        a0 = fmaf(v.y, lo.w, a0); a1 = fmaf(v.y, hi.x, a1);
                        a2 = fmaf(v.y, hi.y, a2); a3 = fmaf(v.y, hi.z, a3);
                        a0 = fmaf(v.z, lo.z, a0); a1 = fmaf(v.z, lo.w, a1);
                        a2 = fmaf(v.z, hi.x, a2); a3 = fmaf(v.z, hi.y, a3);
                        a0 = fmaf(v.w, lo.y, a0); a1 = fmaf(v.w, lo.z, a1);
                        a2 = fmaf(v.w, lo.w, a2); a3 = fmaf(v.w, hi.x, a3);
                    }
                }
                // ---- Phase B: g = 8..15 + the i=64 tap, window f4s 0..8 ----
                {
                    f4 wB[9];
                    #pragma unroll
                    for (int j = 0; j < 9; ++j) wB[j] = Rl4[q + j];
                    #pragma unroll
                    for (int g2 = 0; g2 < 8; ++g2) {
                        const f4 v  = V4[8 + g2];
                        const f4 hi = wB[8 - g2];
                        const f4 lo = wB[7 - g2];
                        a0 = fmaf(v.x, hi.x, a0); a1 = fmaf(v.x, hi.y, a1);
                        a2 = fmaf(v.x, hi.z, a2); a3 = fmaf(v.x, hi.w, a3);
                        a0 = fmaf(v.y, lo.w, a0); a1 = fmaf(v.y, hi.x, a1);
                        a2 = fmaf(v.y, hi.y, a2); a3 = fmaf(v.y, hi.z, a3);
                        a0 = fmaf(v.z, lo.z, a0); a1 = fmaf(v.z, lo.w, a1);
                        a2 = fmaf(v.z, hi.x, a2); a3 = fmaf(v.z, hi.y, a3);
                        a0 = fmaf(v.w, lo.y, a0); a1 = fmaf(v.w, lo.z, a1);
                        a2 = fmaf(v.w, lo.w, a2); a3 = fmaf(v.w, hi.x, a3);
                    }
                    const float v64 = Vs[64];
                    a0 = fmaf(v64, wB[0].x, a0); a1 = fmaf(v64, wB[0].y, a1);
                    a2 = fmaf(v64, wB[0].z, a2); a3 = fmaf(v64, wB[0].w, a3);
                }
                f4 o; o.x = a0; o.y = a1; o.z = a2; o.w = a3;
                Rl4w[((L + 64) >> 2) + q] = o;
            }
        }
        __syncthreads();
    }

    for (int j = tid; j < K1_LEN / 4; j += K1_THREADS)
        reinterpret_cast<f4*>(R)[j] = reinterpret_cast<const f4*>(Rl)[j];
}

// Phase 1b: grid-wide doubling R[0..L) -> R[L..2L). Tail staged through LDS
// so the W sums chain on ~4-cyc FMA latency, not ~200-cyc L2 loads.
__global__ __launch_bounds__(DBLK) void ar_double(const float* __restrict__ params,
                                                  float* __restrict__ R, const int L) {
    __shared__ float p[P];
    __shared__ float tail[P];        // tail[m] = R[L-1-m]
    __shared__ float V[P + 1];
    __shared__ float win[DBLK + P];
    const int tid = threadIdx.x;
    const int B0  = blockIdx.x * DBLK;
    if (tid < P) {
        p[tid] = params[tid];
        tail[tid] = R[L - 1 - tid];
    }
    for (int j = tid; j < DBLK + P; j += DBLK) {
        const int g = B0 - P + j;
        win[j] = (g >= 0) ? R[g] : 0.f;   // zero-pad only affects block 0
    }
    __syncthreads();
    if (tid <= P) {
        const int j = tid;
        float W0 = 0.f, W1 = 0.f;
        if (j <= P - 1)
            for (int m = 0; m <= P - 1 - j; ++m) W0 = fmaf(p[m + j], tail[m], W0);
        if (j >= 1)
            for (int m = 0; m <= P - j; ++m) W1 = fmaf(p[m + j - 1], tail[m], W1);
        V[j] = W0 - W1;
    }
    __syncthreads();
    float acc = win[P + tid];
    #pragma unroll
    for (int i = 0; i <= P; ++i) acc = fmaf(V[i], win[P + tid - i], acc);
    R[L + B0 + tid] = acc;
}

// Phase 2: out[b,t] = bias*R[t] + 0.3*noise[b,t]  (memory-bound, float4,
// nontemporal on the 128 MB streaming traffic so R stays L2-resident)
__global__ __launch_bounds__(256) void ar_out(const float* __restrict__ R,
                                              const float* __restrict__ bias,
                                              const float* __restrict__ noise,
                                              float* __restrict__ out) {
    const int i4 = blockIdx.x * 256 + threadIdx.x;       // float4 index
    const float b = bias[0];
    const int t4 = i4 & (T_LEN / 4 - 1);                 // T divisible by 4
    const f4 r4 = reinterpret_cast<const f4*>(R)[t4];
    const f4 n4 = __builtin_nontemporal_load(reinterpret_cast<const f4*>(noise) + i4);
    f4 o;
    o.x = fmaf(0.3f, n4.x, b * r4.x);
    o.y = fmaf(0.3f, n4.y, b * r4.y);
    o.z = fmaf(0.3f, n4.z, b * r4.z);
    o.w = fmaf(0.3f, n4.w, b * r4.w);
    __builtin_nontemporal_store(o, reinterpret_cast<f4*>(out) + i4);
}

extern "C" void kernel_launch(void* const* d_in, const int* in_sizes, int n_in,
                              void* d_out, int out_size, void* d_ws, size_t ws_size,
                              hipStream_t stream) {
    const float* params = (const float*)d_in[0];
    const float* bias   = (const float*)d_in[1];
    const float* noise  = (const float*)d_in[2];
    float* out = (float*)d_out;
    float* R   = (float*)d_ws;              // 65536 floats = 256 KiB scratch

    hipLaunchKernelGGL(ar_k1, dim3(1), dim3(K1_THREADS), 0, stream, params, R);
    for (int L = K1_LEN; L < T_LEN; L <<= 1)
        hipLaunchKernelGGL(ar_double, dim3(L / DBLK), dim3(DBLK), 0, stream,
                           params, R, L);
    hipLaunchKernelGGL(ar_out, dim3((BATCH * (T_LEN / 4)) / 256), dim3(256),
                       0, stream, R, bias, noise, out);
}

// Round 5
// 174.953 us; speedup vs baseline: 1.4222x; 1.4222x over previous
//
#include <hip/hip_runtime.h>

#define T_LEN   65536
#define BATCH   256
#define P       64
#define K1_LEN  8192
#define K1_THREADS 256
#define DBLK    256

typedef float f4 __attribute__((ext_vector_type(4)));

// ---------------------------------------------------------------------------
// means[t] = bias * R[t] where R is the STEP RESPONSE of the AR(64) filter:
//   R[t] = sum_k params[k]*R[t-1-k] + 1,  R[t<0] = 0
// Extension identity:
//   R[L+tau] = R[tau] + sum_{i=0}^{64} V[i]*R[tau-i]
//   V[i] = W[i]-W[i-1],  W[j] = sum_{m=0}^{63-j} params[m+j]*R[L-1-m]
// ---------------------------------------------------------------------------

// Phase 1a: serial 64 steps + in-LDS doubling 64 -> 8192, single workgroup.
// R4: 256 threads + __launch_bounds__(256,1) = 1 wave/SIMD = 512-VGPR budget.
// The 17xf4 register window (~100 VGPRs live) now fits with headroom.
// History: 1024thr/64VGPR spilled (244us), 512thr/128VGPR spilled ~30
// floats/quad (113us, WRITE 226KB); source-level phase-splitting (R3) was
// defeated by load hoisting — identical codegen. Only the budget matters.
__global__ __launch_bounds__(K1_THREADS, 1) void ar_k1(const float* __restrict__ params,
                                                       float* __restrict__ R) {
    __shared__ __align__(16) float Rl[K1_LEN];
    __shared__ float p[P];
    __shared__ __align__(16) float Vs[68];
    const int tid = threadIdx.x;
    if (tid < P) p[tid] = params[tid];
    __syncthreads();

    // Serial stage: lane k holds transposed-form state z_{k+1}.
    if (tid < 64) {
        float z = 0.f;
        const float pk = p[tid];
        for (int t = 0; t < 64; ++t) {
            float y  = __shfl(z, 0) + 1.0f;   // R[t]
            float zn = __shfl_down(z, 1);
            if (tid == 63) zn = 0.f;
            z = fmaf(pk, y, zn);
            if (tid == 0) Rl[t] = y;
        }
    }
    __syncthreads();

    for (int L = 64; L < K1_LEN; L <<= 1) {
        if (tid <= P) {
            const int j = tid;
            float W0 = 0.f, W1 = 0.f;
            if (j <= P - 1)
                for (int m = 0; m <= P - 1 - j; ++m) W0 = fmaf(p[m + j], Rl[L - 1 - m], W0);
            if (j >= 1)
                for (int m = 0; m <= P - j; ++m) W1 = fmaf(p[m + j - 1], Rl[L - 1 - m], W1);
            Vs[j] = W0 - W1;
        }
        __syncthreads();
        // boundary outputs tau in [0,64): R[tau-i]=0 for i>tau
        if (tid < 64) {
            const int tau = tid;
            float acc = Rl[tau];
            for (int i = 0; i <= tau; ++i) acc = fmaf(Vs[i], Rl[tau - i], acc);
            Rl[L + tau] = acc;
        }
        // blocked outputs tau in [64,L): 4 per quad. Window floats
        // Rl[4q..4q+67] = f4s w[0..16]; tap group g uses hi=w[16-g], lo=w[15-g].
        {
            const f4* __restrict__ Rl4 = reinterpret_cast<const f4*>(Rl);
            f4* __restrict__ Rl4w = reinterpret_cast<f4*>(Rl);
            const f4* __restrict__ V4 = reinterpret_cast<const f4*>(Vs);
            const int nq = (L - 64) >> 2;
            #pragma unroll 1
            for (int q = tid; q < nq; q += K1_THREADS) {
                f4 w4[17];
                #pragma unroll
                for (int j = 0; j < 17; ++j) w4[j] = Rl4[q + j];
                float a0 = w4[16].x, a1 = w4[16].y, a2 = w4[16].z, a3 = w4[16].w;
                #pragma unroll
                for (int g = 0; g < 16; ++g) {   // i = 4g..4g+3
                    const f4 v  = V4[g];
                    const f4 hi = w4[16 - g];
                    const f4 lo = w4[15 - g];
                    a0 = fmaf(v.x, hi.x, a0); a1 = fmaf(v.x, hi.y, a1);
                    a2 = fmaf(v.x, hi.z, a2); a3 = fmaf(v.x, hi.w, a3);
                    a0 = fmaf(v.y, lo.w, a0); a1 = fmaf(v.y, hi.x, a1);
                    a2 = fmaf(v.y, hi.y, a2); a3 = fmaf(v.y, hi.z, a3);
                    a0 = fmaf(v.z, lo.z, a0); a1 = fmaf(v.z, lo.w, a1);
                    a2 = fmaf(v.z, hi.x, a2); a3 = fmaf(v.z, hi.y, a3);
                    a0 = fmaf(v.w, lo.y, a0); a1 = fmaf(v.w, lo.z, a1);
                    a2 = fmaf(v.w, lo.w, a2); a3 = fmaf(v.w, hi.x, a3);
                }
                const float v64 = Vs[64];     // i = 64 -> floats 0..3
                a0 = fmaf(v64, w4[0].x, a0); a1 = fmaf(v64, w4[0].y, a1);
                a2 = fmaf(v64, w4[0].z, a2); a3 = fmaf(v64, w4[0].w, a3);
                f4 o; o.x = a0; o.y = a1; o.z = a2; o.w = a3;
                Rl4w[((L + 64) >> 2) + q] = o;
            }
        }
        __syncthreads();
    }

    for (int j = tid; j < K1_LEN / 4; j += K1_THREADS)
        reinterpret_cast<f4*>(R)[j] = reinterpret_cast<const f4*>(Rl)[j];
}

// Phase 1b: grid-wide doubling R[0..L) -> R[L..2L). Tail staged through LDS
// so the W sums chain on ~4-cyc FMA latency, not ~200-cyc L2 loads.
__global__ __launch_bounds__(DBLK) void ar_double(const float* __restrict__ params,
                                                  float* __restrict__ R, const int L) {
    __shared__ float p[P];
    __shared__ float tail[P];        // tail[m] = R[L-1-m]
    __shared__ float V[P + 1];
    __shared__ float win[DBLK + P];
    const int tid = threadIdx.x;
    const int B0  = blockIdx.x * DBLK;
    if (tid < P) {
        p[tid] = params[tid];
        tail[tid] = R[L - 1 - tid];
    }
    for (int j = tid; j < DBLK + P; j += DBLK) {
        const int g = B0 - P + j;
        win[j] = (g >= 0) ? R[g] : 0.f;   // zero-pad only affects block 0
    }
    __syncthreads();
    if (tid <= P) {
        const int j = tid;
        float W0 = 0.f, W1 = 0.f;
        if (j <= P - 1)
            for (int m = 0; m <= P - 1 - j; ++m) W0 = fmaf(p[m + j], tail[m], W0);
        if (j >= 1)
            for (int m = 0; m <= P - j; ++m) W1 = fmaf(p[m + j - 1], tail[m], W1);
        V[j] = W0 - W1;
    }
    __syncthreads();
    float acc = win[P + tid];
    #pragma unroll
    for (int i = 0; i <= P; ++i) acc = fmaf(V[i], win[P + tid - i], acc);
    R[L + B0 + tid] = acc;
}

// Phase 2: out[b,t] = bias*R[t] + 0.3*noise[b,t]  (memory-bound, float4,
// nontemporal on the 128 MB streaming traffic so R stays L2-resident)
__global__ __launch_bounds__(256) void ar_out(const float* __restrict__ R,
                                              const float* __restrict__ bias,
                                              const float* __restrict__ noise,
                                              float* __restrict__ out) {
    const int i4 = blockIdx.x * 256 + threadIdx.x;       // float4 index
    const float b = bias[0];
    const int t4 = i4 & (T_LEN / 4 - 1);                 // T divisible by 4
    const f4 r4 = reinterpret_cast<const f4*>(R)[t4];
    const f4 n4 = __builtin_nontemporal_load(reinterpret_cast<const f4*>(noise) + i4);
    f4 o;
    o.x = fmaf(0.3f, n4.x, b * r4.x);
    o.y = fmaf(0.3f, n4.y, b * r4.y);
    o.z = fmaf(0.3f, n4.z, b * r4.z);
    o.w = fmaf(0.3f, n4.w, b * r4.w);
    __builtin_nontemporal_store(o, reinterpret_cast<f4*>(out) + i4);
}

extern "C" void kernel_launch(void* const* d_in, const int* in_sizes, int n_in,
                              void* d_out, int out_size, void* d_ws, size_t ws_size,
                              hipStream_t stream) {
    const float* params = (const float*)d_in[0];
    const float* bias   = (const float*)d_in[1];
    const float* noise  = (const float*)d_in[2];
    float* out = (float*)d_out;
    float* R   = (float*)d_ws;              // 65536 floats = 256 KiB scratch

    hipLaunchKernelGGL(ar_k1, dim3(1), dim3(K1_THREADS), 0, stream, params, R);
    for (int L = K1_LEN; L < T_LEN; L <<= 1)
        hipLaunchKernelGGL(ar_double, dim3(L / DBLK), dim3(DBLK), 0, stream,
                           params, R, L);
    hipLaunchKernelGGL(ar_out, dim3((BATCH * (T_LEN / 4)) / 256), dim3(256),
                       0, stream, R, bias, noise, out);
}

// Round 6
// 167.436 us; speedup vs baseline: 1.4860x; 1.0449x over previous
//
#include <hip/hip_runtime.h>

#define T_LEN   65536
#define BATCH   256
#define P       64
#define K1_LEN  8192
#define K1_THREADS 256
#define DBLK    256

typedef float f4 __attribute__((ext_vector_type(4)));

// ---------------------------------------------------------------------------
// means[t] = bias * R[t] where R is the STEP RESPONSE of the AR(64) filter:
//   R[t] = sum_k params[k]*R[t-1-k] + 1,  R[t<0] = 0
// Extension identity:
//   R[L+tau] = R[tau] + sum_{i=0}^{64} V[i]*R[tau-i]
//   V[j] = W0[j] - W0[j-1],  W0[j] = sum_{m=0}^{63-j} params[m+j]*R[L-1-m]
//   (W0[-1] = W0[64] = 0; derivation: the old W1(j) == W0(j-1))
// R5: lane-VARIABLE trip-count loops (V chain, boundary) were emitting
// ~64x latency-serialized ds_read+waitcnt per level (~80K cyc total = the
// missing 34 us of ar_k1). All loops now have FIXED trip counts (masking via
// zero-padded p / index clamp) so they fully unroll and pipeline.
// ---------------------------------------------------------------------------

__global__ __launch_bounds__(K1_THREADS, 1) void ar_k1(const float* __restrict__ params,
                                                       float* __restrict__ R) {
    __shared__ __align__(16) float Rl[K1_LEN];
    __shared__ float p[128];          // zero-padded: p[64..127] = 0 masks m+j>63
    __shared__ float Wp[64][4];
    __shared__ __align__(16) float Vs[68];
    const int tid = threadIdx.x;
    if (tid < 128) p[tid] = (tid < P) ? params[tid] : 0.f;
    __syncthreads();

    // Serial stage: lane k holds transposed-form state z_{k+1}.
    if (tid < 64) {
        float z = 0.f;
        const float pk = p[tid];
        for (int t = 0; t < 64; ++t) {
            float y  = __shfl(z, 0) + 1.0f;   // R[t]
            float zn = __shfl_down(z, 1);
            if (tid == 63) zn = 0.f;
            z = fmaf(pk, y, zn);
            if (tid == 0) Rl[t] = y;
        }
    }
    __syncthreads();

    for (int L = 64; L <= K1_LEN; L <<= 1) {
        const bool last = (L == K1_LEN);   // last level streams to global
        // ---- V taps, wave-parallel: thread (j=tid>>2, c=tid&3) does a
        //      16-wide partial of W0[j]; fixed trips, fully unrolled. ----
        {
            const int j = tid >> 2, c = tid & 3;
            const int mbase = c << 4;
            float w = 0.f;
            #pragma unroll
            for (int mm = 0; mm < 16; ++mm) {
                const int m = mbase + mm;
                w = fmaf(p[m + j], Rl[L - 1 - m], w);  // p pad masks m+j>63
            }
            Wp[j][c] = w;
        }
        __syncthreads();
        if (tid <= P) {
            const float wj  = (tid < P)
                ? (Wp[tid][0] + Wp[tid][1] + Wp[tid][2] + Wp[tid][3]) : 0.f;
            const float wm1 = (tid >= 1)
                ? (Wp[tid-1][0] + Wp[tid-1][1] + Wp[tid-1][2] + Wp[tid-1][3]) : 0.f;
            Vs[tid] = wj - wm1;
        }
        __syncthreads();
        // ---- boundary outputs tau in [0,64): fixed 64 trips, clamped idx ----
        if (tid < P) {
            const int tau = tid;
            float acc = Rl[tau];
            #pragma unroll
            for (int i = 0; i < P; ++i) {
                const int idx = (tau - i) > 0 ? (tau - i) : 0;    // v_max
                const float v = (i <= tau) ? Vs[i] : 0.f;         // v_cndmask
                acc = fmaf(v, Rl[idx], acc);
            }
            if (last) R[L + tau] = acc; else Rl[L + tau] = acc;
        }
        // ---- blocked outputs tau in [64,L): 4 per quad, 17xf4 window ----
        {
            const f4* __restrict__ Rl4 = reinterpret_cast<const f4*>(Rl);
            f4* __restrict__ Rl4w = reinterpret_cast<f4*>(Rl);
            f4* __restrict__ Rg4  = reinterpret_cast<f4*>(R);
            const f4* __restrict__ V4 = reinterpret_cast<const f4*>(Vs);
            const int nq = (L - 64) >> 2;
            #pragma unroll 1
            for (int q = tid; q < nq; q += K1_THREADS) {
                f4 w4[17];
                #pragma unroll
                for (int j = 0; j < 17; ++j) w4[j] = Rl4[q + j];
                float a0 = w4[16].x, a1 = w4[16].y, a2 = w4[16].z, a3 = w4[16].w;
                #pragma unroll
                for (int g = 0; g < 16; ++g) {   // i = 4g..4g+3
                    const f4 v  = V4[g];
                    const f4 hi = w4[16 - g];
                    const f4 lo = w4[15 - g];
                    a0 = fmaf(v.x, hi.x, a0); a1 = fmaf(v.x, hi.y, a1);
                    a2 = fmaf(v.x, hi.z, a2); a3 = fmaf(v.x, hi.w, a3);
                    a0 = fmaf(v.y, lo.w, a0); a1 = fmaf(v.y, hi.x, a1);
                    a2 = fmaf(v.y, hi.y, a2); a3 = fmaf(v.y, hi.z, a3);
                    a0 = fmaf(v.z, lo.z, a0); a1 = fmaf(v.z, lo.w, a1);
                    a2 = fmaf(v.z, hi.x, a2); a3 = fmaf(v.z, hi.y, a3);
                    a0 = fmaf(v.w, lo.y, a0); a1 = fmaf(v.w, lo.z, a1);
                    a2 = fmaf(v.w, lo.w, a2); a3 = fmaf(v.w, hi.x, a3);
                }
                const float v64 = Vs[64];     // i = 64 -> floats 0..3
                a0 = fmaf(v64, w4[0].x, a0); a1 = fmaf(v64, w4[0].y, a1);
                a2 = fmaf(v64, w4[0].z, a2); a3 = fmaf(v64, w4[0].w, a3);
                f4 o; o.x = a0; o.y = a1; o.z = a2; o.w = a3;
                if (last) Rg4[((L + 64) >> 2) + q] = o;
                else      Rl4w[((L + 64) >> 2) + q] = o;
            }
        }
        __syncthreads();
    }

    for (int j = tid; j < K1_LEN / 4; j += K1_THREADS)
        reinterpret_cast<f4*>(R)[j] = reinterpret_cast<const f4*>(Rl)[j];
}

// Phase 1b: grid-wide doubling R[0..L) -> R[L..2L). Parallel V (same fix).
__global__ __launch_bounds__(DBLK) void ar_double(const float* __restrict__ params,
                                                  float* __restrict__ R, const int L) {
    __shared__ float p[128];
    __shared__ float tl[P];          // tl[m] = R[L-1-m]
    __shared__ float Wp[64][4];
    __shared__ float V[P + 1];
    __shared__ float win[DBLK + P];
    const int tid = threadIdx.x;
    const int B0  = blockIdx.x * DBLK;
    if (tid < 128) p[tid] = (tid < P) ? params[tid] : 0.f;
    if (tid < P)   tl[tid] = R[L - 1 - tid];
    for (int j = tid; j < DBLK + P; j += DBLK) {
        const int g = B0 - P + j;
        win[j] = (g >= 0) ? R[g] : 0.f;   // zero-pad only affects block 0
    }
    __syncthreads();
    {
        const int j = tid >> 2, c = tid & 3;
        const int mbase = c << 4;
        float w = 0.f;
        #pragma unroll
        for (int mm = 0; mm < 16; ++mm) {
            const int m = mbase + mm;
            w = fmaf(p[m + j], tl[m], w);
        }
        Wp[j][c] = w;
    }
    __syncthreads();
    if (tid <= P) {
        const float wj  = (tid < P)
            ? (Wp[tid][0] + Wp[tid][1] + Wp[tid][2] + Wp[tid][3]) : 0.f;
        const float wm1 = (tid >= 1)
            ? (Wp[tid-1][0] + Wp[tid-1][1] + Wp[tid-1][2] + Wp[tid-1][3]) : 0.f;
        V[tid] = wj - wm1;
    }
    __syncthreads();
    float acc = win[P + tid];
    #pragma unroll
    for (int i = 0; i <= P; ++i) acc = fmaf(V[i], win[P + tid - i], acc);
    R[L + B0 + tid] = acc;
}

// Phase 2: out[b,t] = bias*R[t] + 0.3*noise[b,t]  (memory-bound, float4,
// nontemporal on the 128 MB streaming traffic so R stays L2-resident)
__global__ __launch_bounds__(256) void ar_out(const float* __restrict__ R,
                                              const float* __restrict__ bias,
                                              const float* __restrict__ noise,
                                              float* __restrict__ out) {
    const int i4 = blockIdx.x * 256 + threadIdx.x;       // float4 index
    const float b = bias[0];
    const int t4 = i4 & (T_LEN / 4 - 1);                 // T divisible by 4
    const f4 r4 = reinterpret_cast<const f4*>(R)[t4];
    const f4 n4 = __builtin_nontemporal_load(reinterpret_cast<const f4*>(noise) + i4);
    f4 o;
    o.x = fmaf(0.3f, n4.x, b * r4.x);
    o.y = fmaf(0.3f, n4.y, b * r4.y);
    o.z = fmaf(0.3f, n4.z, b * r4.z);
    o.w = fmaf(0.3f, n4.w, b * r4.w);
    __builtin_nontemporal_store(o, reinterpret_cast<f4*>(out) + i4);
}

extern "C" void kernel_launch(void* const* d_in, const int* in_sizes, int n_in,
                              void* d_out, int out_size, void* d_ws, size_t ws_size,
                              hipStream_t stream) {
    const float* params = (const float*)d_in[0];
    const float* bias   = (const float*)d_in[1];
    const float* noise  = (const float*)d_in[2];
    float* out = (float*)d_out;
    float* R   = (float*)d_ws;              // 65536 floats = 256 KiB scratch

    // K1 now produces R[0..16384) (last level streams to global)
    hipLaunchKernelGGL(ar_k1, dim3(1), dim3(K1_THREADS), 0, stream, params, R);
    for (int L = 2 * K1_LEN; L < T_LEN; L <<= 1)   // 16384 -> 32768 -> 65536
        hipLaunchKernelGGL(ar_double, dim3(L / DBLK), dim3(DBLK), 0, stream,
                           params, R, L);
    hipLaunchKernelGGL(ar_out, dim3((BATCH * (T_LEN / 4)) / 256), dim3(256),
                       0, stream, R, bias, noise, out);
}